// Round 1
// baseline (3747.058 us; speedup 1.0000x reference)
//
#include <hip/hip_runtime.h>

// SSMTrack: B=8, S=4096, H=1024, D=256
//   inp = x @ W_in + b_in                    (bf16 MFMA GEMM)
//   s_t = tanh(inp_t + s_{t-1} @ W_state + b_state)   (fp32 scan, 1 WG/batch)
//   out = states @ W_out + b_out             (bf16 MFMA GEMM)

typedef float v2f __attribute__((ext_vector_type(2)));
typedef float v4f __attribute__((ext_vector_type(4)));
typedef __bf16 bf16x4 __attribute__((ext_vector_type(4)));
typedef __bf16 bf16x8 __attribute__((ext_vector_type(8)));

#define BARRIER_LGKM() asm volatile("s_waitcnt lgkmcnt(0)\n\ts_barrier" ::: "memory")

// ---------------------------------------------------------------- conversions
__global__ void cvt_f32_bf16_x4(const float* __restrict__ in,
                                __bf16* __restrict__ out, int n4) {
  int i = blockIdx.x * blockDim.x + threadIdx.x;
  if (i >= n4) return;
  v4f v = ((const v4f*)in)[i];
  bf16x4 o;
  o.x = (__bf16)v.x; o.y = (__bf16)v.y; o.z = (__bf16)v.z; o.w = (__bf16)v.w;
  ((bf16x4*)out)[i] = o;
}

// in: [K,N] f32 row-major  ->  out: [N,K] bf16 row-major (i.e. B^T)
__global__ void transpose_cvt(const float* __restrict__ in,
                              __bf16* __restrict__ out, int K, int N) {
  int i = blockIdx.x * blockDim.x + threadIdx.x;
  if (i >= K * N) return;
  int k = i / N;
  int n = i - k * N;
  out[(size_t)n * K + k] = (__bf16)in[i];
}

// ---------------------------------------------------------------- GEMM (bf16)
// C[M,N] (f32) = A[M,K](bf16, row-major) * B  where Bt[N,K] = B^T (bf16)
// One wave per 16x16 C-tile, fragments loaded straight from global.
// A-frag: lane holds A[m = mt*16 + (l&15)][k0 + (l>>4)*8 + j], j=0..7
// B-frag: lane holds B[k0 + (l>>4)*8 + j][n = nt*16 + (l&15)] = Bt[n][k...]
// C/D:    col = l&15, row = (l>>4)*4 + i   (m89-verified)
__global__ void gemm_bt(const __bf16* __restrict__ A,
                        const __bf16* __restrict__ Bt,
                        const float* __restrict__ bias,
                        float* __restrict__ C,
                        int M, int N, int K) {
  int wid  = (blockIdx.x * blockDim.x + threadIdx.x) >> 6;
  int lane = threadIdx.x & 63;
  int ntiles = N >> 4;
  int mt = wid / ntiles;          // nt inner so consecutive waves share A rows
  int nt = wid - mt * ntiles;
  if (mt * 16 >= M) return;
  int r = lane & 15;
  int q = lane >> 4;
  const __bf16* arow = A + (size_t)(mt * 16 + r) * K + q * 8;
  const __bf16* brow = Bt + (size_t)(nt * 16 + r) * K + q * 8;
  v4f acc = {0.f, 0.f, 0.f, 0.f};
  for (int k = 0; k < K; k += 32) {
    bf16x8 af = *(const bf16x8*)(arow + k);
    bf16x8 bf = *(const bf16x8*)(brow + k);
    acc = __builtin_amdgcn_mfma_f32_16x16x32_bf16(af, bf, acc, 0, 0, 0);
  }
  int col = nt * 16 + r;
  float bv = bias[col];
  size_t base = (size_t)(mt * 16 + q * 4) * N + col;
#pragma unroll
  for (int i = 0; i < 4; ++i) C[base + (size_t)i * N] = acc[i] + bv;
}

// ---------------------------------------------------------------- scan
// One workgroup per batch. 1024 threads: d = tid&255 (output column),
// kb = tid>>6... kb = tid>>8 in {0..3} (64-wide k-slice).
// W_state slice lives in registers (64 f32/thread). State in LDS,
// broadcast-read as float4. Two raw s_barriers per step (lgkm-only wait,
// so the u-prefetch global load and bf16 state store stay in flight).
__global__ __launch_bounds__(1024) void scan_kernel(
    const float* __restrict__ inp,      // [B*S, 256] f32
    const float* __restrict__ Wst,      // [256, 256] f32
    const float* __restrict__ b_state,  // [256] f32
    __bf16* __restrict__ states,        // [B*S, 256] bf16 (out)
    int S) {
  const int tid = threadIdx.x;
  const int d = tid & 255;
  const int kb = tid >> 8;
  const int b = blockIdx.x;

  __shared__ float s_lds[256];
  __shared__ float red[3 * 256];
  if (tid < 256) s_lds[tid] = 0.f;  // state0 = 0

  // W2[j] = (W[kb*64+2j][d], W[kb*64+2j+1][d])
  v2f W2[32];
#pragma unroll
  for (int j = 0; j < 32; ++j) {
    float w0 = Wst[(size_t)(kb * 64 + 2 * j) * 256 + d];
    float w1 = Wst[(size_t)(kb * 64 + 2 * j + 1) * 256 + d];
    v2f w; w.x = w0; w.y = w1;
    W2[j] = w;
  }
  const float bst = b_state[d];
  const float* inpb = inp + (size_t)b * S * 256;
  __bf16* stb = states + (size_t)b * S * 256;

  float u = (kb == 0) ? inpb[d] : 0.f;  // prefetch t=0
  BARRIER_LGKM();

  for (int t = 0; t < S; ++t) {
    // partial[d,kb] = sum_{k in slice} s[k] * W[k][d]
    const v4f* sv = (const v4f*)(s_lds + kb * 64);
    v2f acc0; acc0.x = 0.f; acc0.y = 0.f;
    v2f acc1; acc1.x = 0.f; acc1.y = 0.f;
#pragma unroll
    for (int q = 0; q < 16; ++q) {
      v4f s4 = sv[q];  // same addr across wave -> LDS broadcast
      acc0 = __builtin_elementwise_fma(s4.xy, W2[2 * q], acc0);
      acc1 = __builtin_elementwise_fma(s4.zw, W2[2 * q + 1], acc1);
    }
    v2f accs = acc0 + acc1;
    float part = accs.x + accs.y;

    if (kb) red[(kb - 1) * 256 + d] = part;
    BARRIER_LGKM();

    if (kb == 0) {
      float xv = part + red[d] + red[256 + d] + red[512 + d] + u + bst;
      float e = __expf(2.f * xv);
      float sn = 1.f - 2.f / (e + 1.f);  // tanh(xv)
      s_lds[d] = sn;
      stb[(size_t)t * 256 + d] = (__bf16)sn;       // fire-and-forget store
      if (t + 1 < S) u = inpb[(size_t)(t + 1) * 256 + d];  // prefetch next u
    }
    BARRIER_LGKM();
  }
}

// ---------------------------------------------------------------- launch
extern "C" void kernel_launch(void* const* d_in, const int* in_sizes, int n_in,
                              void* d_out, int out_size, void* d_ws,
                              size_t ws_size, hipStream_t stream) {
  const float* x       = (const float*)d_in[0];  // [8,4096,1024]
  const float* W_in    = (const float*)d_in[1];  // [1024,256]
  const float* b_in    = (const float*)d_in[2];  // [256]
  const float* W_state = (const float*)d_in[3];  // [256,256]
  const float* b_state = (const float*)d_in[4];  // [256]
  const float* W_out   = (const float*)d_in[5];  // [256,1024]
  const float* b_out   = (const float*)d_in[6];  // [1024]
  float* out = (float*)d_out;                    // [8,4096,1024]

  const int B = 8, S = 4096, H = 1024, D = 256;
  const int M = B * S;  // 32768

  char* ws = (char*)d_ws;
  float*  inp    = (float*)(ws + 0);            // 32 MB  [M,D] f32
  __bf16* states = (__bf16*)(ws + 33554432);    // 16 MB  [M,D] bf16
  __bf16* xb     = (__bf16*)(ws + 50331648);    // 64 MB  [M,H] bf16
  __bf16* WinT   = (__bf16*)(ws + 117440512);   // 0.5 MB [D,H] bf16  (W_in^T)
  __bf16* WoutT  = (__bf16*)(ws + 117964800);   // 0.5 MB [H,D] bf16  (W_out^T)

  // conversions
  cvt_f32_bf16_x4<<<(M * H / 4 + 255) / 256, 256, 0, stream>>>(x, xb, M * H / 4);
  transpose_cvt<<<(H * D + 255) / 256, 256, 0, stream>>>(W_in, WinT, H, D);
  transpose_cvt<<<(D * H + 255) / 256, 256, 0, stream>>>(W_out, WoutT, D, H);

  // phase 1: inp = x @ W_in + b_in   (M=32768, N=256, K=1024)
  {
    int waves = (M / 16) * (D / 16);
    gemm_bt<<<waves / 4, 256, 0, stream>>>(xb, WinT, b_in, inp, M, D, H);
  }

  // phase 2: sequential scan, one WG per batch
  scan_kernel<<<B, 1024, 0, stream>>>(inp, W_state, b_state, states, S);

  // phase 3: out = states @ W_out + b_out   (M=32768, N=1024, K=256)
  {
    int waves = (M / 16) * (H / 16);
    gemm_bt<<<waves / 4, 256, 0, stream>>>(states, WoutT, b_out, out, M, H, D);
  }
}

// Round 2
// 3486.422 us; speedup vs baseline: 1.0748x; 1.0748x over previous
//
#include <hip/hip_runtime.h>

// SSMTrack: B=8, S=4096, H=1024, D=256
//   inp = x @ W_in + b_in                    (bf16 MFMA GEMM)
//   s_t = tanh(inp_t + s_{t-1} @ W_state + b_state)   (f16-dot2 scan, 1 WG/batch)
//   out = states @ W_out + b_out             (bf16 MFMA GEMM)

typedef float v2f __attribute__((ext_vector_type(2)));
typedef float v4f __attribute__((ext_vector_type(4)));
typedef __bf16 bf16x4 __attribute__((ext_vector_type(4)));
typedef __bf16 bf16x8 __attribute__((ext_vector_type(8)));
typedef _Float16 h2 __attribute__((ext_vector_type(2)));
typedef _Float16 h8 __attribute__((ext_vector_type(8)));

#define BARRIER_LGKM() asm volatile("s_waitcnt lgkmcnt(0)\n\ts_barrier" ::: "memory")

#if __has_builtin(__builtin_amdgcn_fdot2)
#define FDOT2(a, b, c) __builtin_amdgcn_fdot2((a), (b), (c), false)
#else
static __device__ __forceinline__ float FDOT2(h2 a, h2 b, float c) {
  return c + (float)a.x * (float)b.x + (float)a.y * (float)b.y;
}
#endif

// ---------------------------------------------------------------- conversions
__global__ void cvt_f32_bf16_x4(const float* __restrict__ in,
                                __bf16* __restrict__ out, int n4) {
  int i = blockIdx.x * blockDim.x + threadIdx.x;
  if (i >= n4) return;
  v4f v = ((const v4f*)in)[i];
  bf16x4 o;
  o.x = (__bf16)v.x; o.y = (__bf16)v.y; o.z = (__bf16)v.z; o.w = (__bf16)v.w;
  ((bf16x4*)out)[i] = o;
}

// in: [K,N] f32 row-major  ->  out: [N,K] bf16 row-major (i.e. B^T)
__global__ void transpose_cvt(const float* __restrict__ in,
                              __bf16* __restrict__ out, int K, int N) {
  int i = blockIdx.x * blockDim.x + threadIdx.x;
  if (i >= K * N) return;
  int k = i / N;
  int n = i - k * N;
  out[(size_t)n * K + k] = (__bf16)in[i];
}

// ---------------------------------------------------------------- GEMM (bf16)
// C[M,N] (f32) = A[M,K](bf16, row-major) * B  where Bt[N,K] = B^T (bf16)
// One wave per 16x16 C-tile, fragments loaded straight from global.
// C/D: col = l&15, row = (l>>4)*4 + i   (m89-verified)
__global__ void gemm_bt(const __bf16* __restrict__ A,
                        const __bf16* __restrict__ Bt,
                        const float* __restrict__ bias,
                        float* __restrict__ C,
                        int M, int N, int K) {
  int wid  = (blockIdx.x * blockDim.x + threadIdx.x) >> 6;
  int lane = threadIdx.x & 63;
  int ntiles = N >> 4;
  int mt = wid / ntiles;          // nt inner so consecutive waves share A rows
  int nt = wid - mt * ntiles;
  if (mt * 16 >= M) return;
  int r = lane & 15;
  int q = lane >> 4;
  const __bf16* arow = A + (size_t)(mt * 16 + r) * K + q * 8;
  const __bf16* brow = Bt + (size_t)(nt * 16 + r) * K + q * 8;
  v4f acc = {0.f, 0.f, 0.f, 0.f};
  for (int k = 0; k < K; k += 32) {
    bf16x8 af = *(const bf16x8*)(arow + k);
    bf16x8 bf = *(const bf16x8*)(brow + k);
    acc = __builtin_amdgcn_mfma_f32_16x16x32_bf16(af, bf, acc, 0, 0, 0);
  }
  int col = nt * 16 + r;
  float bv = bias[col];
  size_t base = (size_t)(mt * 16 + q * 4) * N + col;
#pragma unroll
  for (int i = 0; i < 4; ++i) C[base + (size_t)i * N] = acc[i] + bv;
}

// ---------------------------------------------------------------- scan
// One block (256 threads = 4 waves, one per SIMD) per batch. Thread owns
// output column d = tid: holds W_state[:, d] as 128 f16-pairs in VGPRs and
// computes the full 256-MAC dot via v_dot2_f32_f16 (fp32 accumulation).
// No cross-thread reduction. State ping-pongs between two LDS f16 buffers;
// single raw barrier per step (lgkm-only wait: the u-prefetch global load
// and the bf16 state store stay in flight across the barrier).
__global__ __launch_bounds__(256) void scan_dot(
    const float* __restrict__ inp,      // [B*S, 256] f32
    const float* __restrict__ Wst,      // [256, 256] f32
    const float* __restrict__ b_state,  // [256] f32
    __bf16* __restrict__ states,        // [B*S, 256] bf16 (out)
    int S) {
  const int tid = threadIdx.x;  // = d, 0..255
  const int b = blockIdx.x;

  __shared__ __align__(16) _Float16 sbuf[2][256];

  // W2[c] = (W[2c][d], W[2c+1][d]) as f16. Loads are coalesced across tid.
  h2 W2[128];
#pragma unroll
  for (int c = 0; c < 128; ++c) {
    h2 w;
    w.x = (_Float16)Wst[(size_t)(2 * c) * 256 + tid];
    w.y = (_Float16)Wst[(size_t)(2 * c + 1) * 256 + tid];
    W2[c] = w;
  }
  const float bst = b_state[tid];
  const float* inpb = inp + (size_t)b * S * 256;
  __bf16* stb = states + (size_t)b * S * 256;

  sbuf[0][tid] = (_Float16)0.f;  // state0 = 0
  float u = inpb[tid];           // u for t=0
  __syncthreads();

  int cur = 0;
  for (int t = 0; t < S; ++t) {
    // prefetch next u early so the ~500cy global latency hides under the dots
    float u_next = 0.f;
    if (t + 1 < S) u_next = inpb[(size_t)(t + 1) * 256 + tid];

    const h2* sp = (const h2*)sbuf[cur];
    float a0 = 0.f, a1 = 0.f, a2 = 0.f, a3 = 0.f;
#pragma unroll
    for (int c = 0; c < 32; ++c) {
      h8 s8 = *(const h8*)(sp + 4 * c);  // ds_read_b128, wave-uniform addr
      h2 p0; p0.x = s8[0]; p0.y = s8[1];
      h2 p1; p1.x = s8[2]; p1.y = s8[3];
      h2 p2; p2.x = s8[4]; p2.y = s8[5];
      h2 p3; p3.x = s8[6]; p3.y = s8[7];
      a0 = FDOT2(p0, W2[4 * c + 0], a0);
      a1 = FDOT2(p1, W2[4 * c + 1], a1);
      a2 = FDOT2(p2, W2[4 * c + 2], a2);
      a3 = FDOT2(p3, W2[4 * c + 3], a3);
    }
    float x = (a0 + a1) + (a2 + a3) + u + bst;

    // tanh(x) = 1 - 2/(exp(2x)+1)
    float e = __expf(2.f * x);
    float sn = 1.f - 2.f * __builtin_amdgcn_rcpf(e + 1.f);

    cur ^= 1;
    sbuf[cur][tid] = (_Float16)sn;           // ds_write_b16
    stb[(size_t)t * 256 + tid] = (__bf16)sn;  // fire-and-forget global store
    u = u_next;
    BARRIER_LGKM();
  }
}

// ---------------------------------------------------------------- launch
extern "C" void kernel_launch(void* const* d_in, const int* in_sizes, int n_in,
                              void* d_out, int out_size, void* d_ws,
                              size_t ws_size, hipStream_t stream) {
  const float* x       = (const float*)d_in[0];  // [8,4096,1024]
  const float* W_in    = (const float*)d_in[1];  // [1024,256]
  const float* b_in    = (const float*)d_in[2];  // [256]
  const float* W_state = (const float*)d_in[3];  // [256,256]
  const float* b_state = (const float*)d_in[4];  // [256]
  const float* W_out   = (const float*)d_in[5];  // [256,1024]
  const float* b_out   = (const float*)d_in[6];  // [1024]
  float* out = (float*)d_out;                    // [8,4096,1024]

  const int B = 8, S = 4096, H = 1024, D = 256;
  const int M = B * S;  // 32768

  char* ws = (char*)d_ws;
  float*  inp    = (float*)(ws + 0);            // 32 MB  [M,D] f32
  __bf16* states = (__bf16*)(ws + 33554432);    // 16 MB  [M,D] bf16
  __bf16* xb     = (__bf16*)(ws + 50331648);    // 64 MB  [M,H] bf16
  __bf16* WinT   = (__bf16*)(ws + 117440512);   // 0.5 MB [D,H] bf16  (W_in^T)
  __bf16* WoutT  = (__bf16*)(ws + 117964800);   // 0.5 MB [H,D] bf16  (W_out^T)

  // conversions
  cvt_f32_bf16_x4<<<(M * H / 4 + 255) / 256, 256, 0, stream>>>(x, xb, M * H / 4);
  transpose_cvt<<<(H * D + 255) / 256, 256, 0, stream>>>(W_in, WinT, H, D);
  transpose_cvt<<<(D * H + 255) / 256, 256, 0, stream>>>(W_out, WoutT, D, H);

  // phase 1: inp = x @ W_in + b_in   (M=32768, N=256, K=1024)
  {
    int waves = (M / 16) * (D / 16);
    gemm_bt<<<waves / 4, 256, 0, stream>>>(xb, WinT, b_in, inp, M, D, H);
  }

  // phase 2: sequential scan, one block (4 waves) per batch
  scan_dot<<<B, 256, 0, stream>>>(inp, W_state, b_state, states, S);

  // phase 3: out = states @ W_out + b_out   (M=32768, N=1024, K=256)
  {
    int waves = (M / 16) * (H / 16);
    gemm_bt<<<waves / 4, 256, 0, stream>>>(states, WoutT, b_out, out, M, H, D);
  }
}